// Round 1
// baseline (118.307 us; speedup 1.0000x reference)
//
#include <hip/hip_runtime.h>

// StericClashConstraint: N=16384 pts [N,3] fp32.
// out[0..3N-1] = pos passthrough; out[3N] = mean(max(1-dist,0), diag=0) * 0.02
//
// Round 7 (this round):
// (a) Per-k hit detection: `if (__ballot(v))` at 64-pair granularity replaces the
//     512-pair OR'd mask + full 8-k rescan. E[hits]=0.39/512 pairs means the old
//     rescan fired on ~32% of j-groups and re-did compares + exec-mask dances;
//     the per-k branch fires ~4.7% and its body is 5 branchless VALU ops.
// (b) Occupancy 16->32 waves/CU: NB=2048 (73728/2048 = 36 columns exact),
//     __launch_bounds__(256,8). VGPR=36 fits the 64-reg cap; hides per-k
//     branch latency + VALU->VCC hazards + scalar-load waits.
// (c) jt4 padded by 8 sentinel entries; all min() clamps dropped -> prefetch
//     addresses are contiguous immediates off one base (s_load merge, no s_min).
// Kept from R4-R6: gram form with thr = 1-|i|^2 threshold trick (no add in fast
// path), repacked float4{x,y,z,sq} wave-uniform j reads (SGPR-resident),
// hw v_sqrt, exact diagonal exclusion via j>i inside the voted predicate.

constexpr int N     = 16384;
constexpr int BLOCK = 256;            // 4 waves
constexpr int IPT   = 8;              // i's per thread
constexpr int IC    = BLOCK * IPT;    // 2048 i's per chunk
constexpr int NXC   = N / IC;         // 8 i-chunks
constexpr int NB    = 2048;           // exactly 8 blocks/CU
constexpr int TCOLS = IC * (NXC * (NXC + 1) / 2);  // 73728 j-columns total
constexpr int CPB   = TCOLS / NB;     // 36 columns per block (exact)
constexpr int QB    = 4;              // j's prefetched per batch
constexpr int JPAD  = 8;              // sentinel pad so prefetch never clamps

__device__ __forceinline__ constexpr int cum(int x) {
    // columns before chunk x: sum_{x'<x} (NXC-x')*IC
    return IC * (x * NXC - x * (x - 1) / 2);
}

template <bool MASKED>
__device__ __forceinline__ float cols(const float4* __restrict__ jt4,
                                      int j0, int len, int ibt,
                                      const float (&xi2)[IPT], const float (&yi2)[IPT],
                                      const float (&zi2)[IPT], const float (&thr)[IPT],
                                      const float (&sqi)[IPT]) {
    float s = 0.0f;
    if (len <= 0) return s;
    float4 cur[QB];
    #pragma unroll
    for (int u = 0; u < QB; ++u) cur[u] = jt4[j0 + u];
    for (int qb = 0; qb < len; qb += QB) {
        float4 nxt[QB];
        #pragma unroll
        for (int u = 0; u < QB; ++u) nxt[u] = jt4[j0 + qb + QB + u];  // pad makes this safe
        #pragma unroll
        for (int u = 0; u < QB; ++u) {
            const float4 pj = cur[u];
            const int jq = j0 + qb + u;
            #pragma unroll
            for (int k = 0; k < IPT; ++k) {
                float d = fmaf(xi2[k], pj.x, pj.w);
                d = fmaf(yi2[k], pj.y, d);
                const float t3 = fmaf(zi2[k], pj.z, d);
                bool v = t3 < thr[k];
                if (MASKED) v = v && (jq > ibt + k * BLOCK);
                if (__builtin_expect(__ballot(v) != 0ull, 0)) {   // ~4.7% taken
                    const float d2 = fmaxf(t3 + sqi[k], 0.0f);
                    const float w  = 1.0f - __builtin_amdgcn_sqrtf(d2);
                    s += v ? w : 0.0f;
                }
            }
        }
        #pragma unroll
        for (int u = 0; u < QB; ++u) cur[u] = nxt[u];
    }
    return s;
}

__global__ void prep_kernel(const float* __restrict__ pos, float* __restrict__ out,
                            float4* __restrict__ jt4) {
    const int t = blockIdx.x * blockDim.x + threadIdx.x;   // 0..16383
    if (t < (N * 3) / 4) {
        reinterpret_cast<float4*>(out)[t] = reinterpret_cast<const float4*>(pos)[t];
    }
    const float x = pos[3 * t], y = pos[3 * t + 1], z = pos[3 * t + 2];
    jt4[t] = make_float4(x, y, z, fmaf(x, x, fmaf(y, y, z * z)));
    if (t < JPAD) {
        // far sentinel: t3 stays astronomically positive, can never pass thr
        jt4[N + t] = make_float4(0.0f, 0.0f, 0.0f, 4e12f);
    }
}

__global__ void __launch_bounds__(BLOCK, 8)
pair_kernel(const float4* __restrict__ jt4, float* __restrict__ out,
            float* __restrict__ acc, unsigned int* __restrict__ cnt) {
    __shared__ float wsum[BLOCK / 64];
    const int b = blockIdx.x;
    const int t = threadIdx.x;

    float s = 0.0f;
    int c = b * CPB;
    const int c1 = c + CPB;

    while (c < c1) {                       // <=2 segments per block
        // uniform: chunk x containing column c
        int x = 0;
        #pragma unroll
        for (int xx = 1; xx < NXC; ++xx)
            if (cum(xx) <= c) x = xx;
        const int segEnd = min(c1, cum(x + 1));
        const int jbase  = x * IC + (c - cum(x));
        const int len    = segEnd - c;     // multiple of 4 by construction
        const int ibt    = x * IC + t;

        // i fragments from the repacked array (one dwordx4 per point)
        float xi2[IPT], yi2[IPT], zi2[IPT], thr[IPT], sqi[IPT];
        #pragma unroll
        for (int k = 0; k < IPT; ++k) {
            const float4 w = jt4[ibt + k * BLOCK];
            xi2[k] = -2.0f * w.x;
            yi2[k] = -2.0f * w.y;
            zi2[k] = -2.0f * w.z;
            sqi[k] = w.w;
            thr[k] = 1.0f - w.w;
        }

        // masked part: columns whose j lies inside this i-chunk (needs j>i)
        const int maskLen = min(len, max(0, (x + 1) * IC - jbase));
        s += cols<true >(jt4, jbase, maskLen, ibt, xi2, yi2, zi2, thr, sqi);
        s += cols<false>(jt4, jbase + maskLen, len - maskLen, ibt, xi2, yi2, zi2, thr, sqi);
        c = segEnd;
    }

    // reduce: wave shuffle -> LDS -> one atomic per block
    for (int off = 32; off > 0; off >>= 1) s += __shfl_down(s, off);
    if ((t & 63) == 0) wsum[t >> 6] = s;
    __syncthreads();
    if (t == 0) {
        float bs = 0.0f;
        #pragma unroll
        for (int w = 0; w < BLOCK / 64; ++w) bs += wsum[w];
        atomicAdd(acc, bs);
        __threadfence();
        const unsigned int done = atomicAdd(cnt, 1u);
        if (done == (unsigned int)(NB - 1)) {          // last block finalizes
            __threadfence();
            const float total = atomicAdd(acc, 0.0f);  // device-coherent read
            const double mean = 2.0 * (double)total / ((double)N * (double)N);
            out[(size_t)N * 3] = (float)(mean * 0.02);
        }
    }
}

extern "C" void kernel_launch(void* const* d_in, const int* in_sizes, int n_in,
                              void* d_out, int out_size, void* d_ws, size_t ws_size,
                              hipStream_t stream) {
    const float* pos = (const float*)d_in[0];
    float* out = (float*)d_out;
    // ws layout: [acc(4B) cnt(4B) pad..256B) | jt4: (16384+8) x float4]
    float* acc = (float*)d_ws;
    unsigned int* cnt = (unsigned int*)d_ws + 1;
    float4* jt4 = (float4*)((char*)d_ws + 256);

    hipMemsetAsync(d_ws, 0, 8, stream);   // acc = 0.f, cnt = 0

    prep_kernel<<<N / 256, 256, 0, stream>>>(pos, out, jt4);
    pair_kernel<<<NB, BLOCK, 0, stream>>>(jt4, out, acc, cnt);
}

// Round 2
// 117.937 us; speedup vs baseline: 1.0031x; 1.0031x over previous
//
#include <hip/hip_runtime.h>

// StericClashConstraint: N=16384 pts [N,3] fp32.
// out[0..3N-1] = pos passthrough; out[3N] = mean(max(1-dist,0), diag=0) * 0.02
//
// Round 8 (this round): FULLY BRANCHLESS inner loop.
// R7 post-mortem: per-k `if(__ballot)` = 8 VALU->VCC->SALU->branch crossings per
// 512 pairs; VALUBusy fell to 31%, pair 42.7->67.4us. Detection machinery costs
// more than the work it guards. So: compute the reference formula directly,
//   s += fmax(1 - sqrt(fmax(d2,0)), 0)
// for every pair. +5 VALU/pair vs the old fast path, but ZERO ballots, ZERO
// SALU ORs, ZERO branches, ZERO rescans. Budget: ~12 issue-slots/pair incl.
// quarter-rate v_sqrt -> ~21us pure issue on 1024 SIMDs; predict ~24us.
// Bonus: exactness improves (old version could add a tiny negative at the
// threshold boundary; the outer clamp now matches jnp.maximum exactly).
// Diagonal/lower-tri excluded by cmp+cndmask on the 12.5% masked fraction.
// Also: acc/cnt zeroed by prep_kernel thread 0 -> memset dispatch removed.
// Kept: repacked float4{x,y,z,sq} wave-uniform j reads (SGPR-resident), QB=4
// prefetch, sentinel pad (branchless handles sentinels for free: w<<0 -> 0),
// NB=2048 exact split (36 cols/block), __launch_bounds__(256,8).

constexpr int N     = 16384;
constexpr int BLOCK = 256;            // 4 waves
constexpr int IPT   = 8;              // i's per thread
constexpr int IC    = BLOCK * IPT;    // 2048 i's per chunk
constexpr int NXC   = N / IC;         // 8 i-chunks
constexpr int NB    = 2048;           // exactly 8 blocks/CU
constexpr int TCOLS = IC * (NXC * (NXC + 1) / 2);  // 73728 j-columns total
constexpr int CPB   = TCOLS / NB;     // 36 columns per block (exact)
constexpr int QB    = 4;              // j's prefetched per batch
constexpr int JPAD  = 8;              // sentinel pad so prefetch never clamps

__device__ __forceinline__ constexpr int cum(int x) {
    // columns before chunk x: sum_{x'<x} (NXC-x')*IC
    return IC * (x * NXC - x * (x - 1) / 2);
}

template <bool MASKED>
__device__ __forceinline__ float cols(const float4* __restrict__ jt4,
                                      int j0, int len, int ibt,
                                      const float (&xi2)[IPT], const float (&yi2)[IPT],
                                      const float (&zi2)[IPT], const float (&sqi)[IPT]) {
    float s = 0.0f;
    if (len <= 0) return s;
    float4 cur[QB];
    #pragma unroll
    for (int u = 0; u < QB; ++u) cur[u] = jt4[j0 + u];
    for (int qb = 0; qb < len; qb += QB) {
        float4 nxt[QB];
        #pragma unroll
        for (int u = 0; u < QB; ++u) nxt[u] = jt4[j0 + qb + QB + u];  // pad makes safe
        #pragma unroll
        for (int u = 0; u < QB; ++u) {
            const float4 pj = cur[u];
            const int jq = j0 + qb + u;
            #pragma unroll
            for (int k = 0; k < IPT; ++k) {
                float d = fmaf(xi2[k], pj.x, pj.w);
                d = fmaf(yi2[k], pj.y, d);
                d = fmaf(zi2[k], pj.z, d);                    // sq_j - 2*dot
                const float d2 = fmaxf(d + sqi[k], 0.0f);     // + sq_i, clamp
                float w = 1.0f - __builtin_amdgcn_sqrtf(d2);  // 1 - dist
                w = fmaxf(w, 0.0f);                            // clamp(min=0)
                if (MASKED) w = (jq > ibt + k * BLOCK) ? w : 0.0f;  // j>i only
                s += w;
            }
        }
        #pragma unroll
        for (int u = 0; u < QB; ++u) cur[u] = nxt[u];
    }
    return s;
}

__global__ void prep_kernel(const float* __restrict__ pos, float* __restrict__ out,
                            float4* __restrict__ jt4,
                            float* __restrict__ acc, unsigned int* __restrict__ cnt) {
    const int t = blockIdx.x * blockDim.x + threadIdx.x;   // 0..16383
    if (t == 0) { *acc = 0.0f; *cnt = 0u; }                // replaces memset
    if (t < (N * 3) / 4) {
        reinterpret_cast<float4*>(out)[t] = reinterpret_cast<const float4*>(pos)[t];
    }
    const float x = pos[3 * t], y = pos[3 * t + 1], z = pos[3 * t + 2];
    jt4[t] = make_float4(x, y, z, fmaf(x, x, fmaf(y, y, z * z)));
    if (t < JPAD) {
        // far sentinel: d2 astronomically positive -> w << 0 -> clamped to 0
        jt4[N + t] = make_float4(0.0f, 0.0f, 0.0f, 4e12f);
    }
}

__global__ void __launch_bounds__(BLOCK, 8)
pair_kernel(const float4* __restrict__ jt4, float* __restrict__ out,
            float* __restrict__ acc, unsigned int* __restrict__ cnt) {
    __shared__ float wsum[BLOCK / 64];
    const int b = blockIdx.x;
    const int t = threadIdx.x;

    float s = 0.0f;
    int c = b * CPB;
    const int c1 = c + CPB;

    while (c < c1) {                       // <=2 segments per block
        // uniform: chunk x containing column c
        int x = 0;
        #pragma unroll
        for (int xx = 1; xx < NXC; ++xx)
            if (cum(xx) <= c) x = xx;
        const int segEnd = min(c1, cum(x + 1));
        const int jbase  = x * IC + (c - cum(x));
        const int len    = segEnd - c;     // multiple of 4 by construction
        const int ibt    = x * IC + t;

        // i fragments from the repacked array (one dwordx4 per point)
        float xi2[IPT], yi2[IPT], zi2[IPT], sqi[IPT];
        #pragma unroll
        for (int k = 0; k < IPT; ++k) {
            const float4 w = jt4[ibt + k * BLOCK];
            xi2[k] = -2.0f * w.x;
            yi2[k] = -2.0f * w.y;
            zi2[k] = -2.0f * w.z;
            sqi[k] = w.w;
        }

        // masked part: columns whose j lies inside this i-chunk (needs j>i)
        const int maskLen = min(len, max(0, (x + 1) * IC - jbase));
        s += cols<true >(jt4, jbase, maskLen, ibt, xi2, yi2, zi2, sqi);
        s += cols<false>(jt4, jbase + maskLen, len - maskLen, ibt, xi2, yi2, zi2, sqi);
        c = segEnd;
    }

    // reduce: wave shuffle -> LDS -> one atomic per block
    for (int off = 32; off > 0; off >>= 1) s += __shfl_down(s, off);
    if ((t & 63) == 0) wsum[t >> 6] = s;
    __syncthreads();
    if (t == 0) {
        float bs = 0.0f;
        #pragma unroll
        for (int w = 0; w < BLOCK / 64; ++w) bs += wsum[w];
        atomicAdd(acc, bs);
        __threadfence();
        const unsigned int done = atomicAdd(cnt, 1u);
        if (done == (unsigned int)(NB - 1)) {          // last block finalizes
            __threadfence();
            const float total = atomicAdd(acc, 0.0f);  // device-coherent read
            const double mean = 2.0 * (double)total / ((double)N * (double)N);
            out[(size_t)N * 3] = (float)(mean * 0.02);
        }
    }
}

extern "C" void kernel_launch(void* const* d_in, const int* in_sizes, int n_in,
                              void* d_out, int out_size, void* d_ws, size_t ws_size,
                              hipStream_t stream) {
    const float* pos = (const float*)d_in[0];
    float* out = (float*)d_out;
    // ws layout: [acc(4B) cnt(4B) pad..256B) | jt4: (16384+8) x float4]
    float* acc = (float*)d_ws;
    unsigned int* cnt = (unsigned int*)d_ws + 1;
    float4* jt4 = (float4*)((char*)d_ws + 256);

    prep_kernel<<<N / 256, 256, 0, stream>>>(pos, out, jt4, acc, cnt);
    pair_kernel<<<NB, BLOCK, 0, stream>>>(jt4, out, acc, cnt);
}